// Round 13
// baseline (648.897 us; speedup 1.0000x reference)
//
#include <hip/hip_runtime.h>

#define BT 16384
#define DK 4096
#define NE 64
#define BM 32                 // rows per block -> grid 512
#define NSQ 16                // steps per wave (K eighth 512 / 32)
#define NPROBS (BT * NE)
#define NIDX (NPROBS)
#define NWTS (NPROBS + BT * 2)

typedef __bf16 bf16x8 __attribute__((ext_vector_type(8)));
typedef float f32x4 __attribute__((ext_vector_type(4)));

__device__ __forceinline__ unsigned asu(float f) { return __builtin_bit_cast(unsigned, f); }
__device__ __forceinline__ float asf(unsigned u) { return __builtin_bit_cast(float, u); }

// Split 8 f32 into 3 bf16 planes (truncation split; residuals exact in f32).
__device__ __forceinline__ void split3(const float* xx, uint4* pl) {
    unsigned h0[8], h1[8], h2[8];
#pragma unroll
    for (int j = 0; j < 8; ++j) {
        const float xf = xx[j];
        const unsigned a0 = asu(xf) & 0xFFFF0000u;
        const float r1 = xf - asf(a0);
        const unsigned a1 = asu(r1) & 0xFFFF0000u;
        const float r2 = r1 - asf(a1);
        const unsigned a2 = asu(r2) & 0xFFFF0000u;
        h0[j] = a0; h1[j] = a1; h2[j] = a2;
    }
    pl[0] = make_uint4((h0[0] >> 16) | (h0[1] & 0xFFFF0000u), (h0[2] >> 16) | (h0[3] & 0xFFFF0000u),
                       (h0[4] >> 16) | (h0[5] & 0xFFFF0000u), (h0[6] >> 16) | (h0[7] & 0xFFFF0000u));
    pl[1] = make_uint4((h1[0] >> 16) | (h1[1] & 0xFFFF0000u), (h1[2] >> 16) | (h1[3] & 0xFFFF0000u),
                       (h1[4] >> 16) | (h1[5] & 0xFFFF0000u), (h1[6] >> 16) | (h1[7] & 0xFFFF0000u));
    pl[2] = make_uint4((h2[0] >> 16) | (h2[1] & 0xFFFF0000u), (h2[2] >> 16) | (h2[3] & 0xFFFF0000u),
                       (h2[4] >> 16) | (h2[5] & 0xFFFF0000u), (h2[6] >> 16) | (h2[7] & 0xFFFF0000u));
}

// prep: W (64 x 4096 f32) -> 3 bf16 planes in B-fragment order (validated R11/R12).
__global__ __launch_bounds__(256) void w_prep(
    const float* __restrict__ W, uint4* __restrict__ WF)
{
    const int g  = blockIdx.x * 256 + threadIdx.x;
    const int e  = g >> 9;
    const int kg = g & 511;
    const float4 v0 = *(const float4*)(W + (long)e * DK + kg * 8);
    const float4 v1 = *(const float4*)(W + (long)e * DK + kg * 8 + 4);
    float xx[8] = {v0.x, v0.y, v0.z, v0.w, v1.x, v1.y, v1.z, v1.w};
    uint4 pl[3];
    split3(xx, pl);
    const int ks = kg >> 2;
    const int l  = (e & 15) | ((kg & 3) << 4);
    const int et = e >> 4;
#pragma unroll
    for (int p = 0; p < 3; ++p)
        WF[((ks * 4 + et) * 3 + p) * 64 + l] = pl[p];
}

// Main: 512 blocks x 32 rows, 16 waves = (eh expert-half) x (kh K-eighth).
// Identical step body to R12 (validated); only residency doubled:
// 1024 threads -> 32 waves/CU = 8 waves/SIMD (VGPR 52 <= 64, LDS 9 KB).
__global__ __attribute__((amdgpu_flat_work_group_size(1024, 1024),
                          amdgpu_waves_per_eu(8)))
void token_router(
    const float* __restrict__ x, const uint4* __restrict__ WF,
    float* __restrict__ out)
{
    __shared__ float lg[BM * 68 + 2 * BM];   // 9 KB: logits + rowm/rowinv

    const int tid  = threadIdx.x;
    const int wv   = tid >> 6;
    const int lane = tid & 63;
    const int eh   = wv & 1;          // expert half
    const int kh   = wv >> 1;         // K eighth 0..7
    const long rowbase = (long)blockIdx.x * BM;

    // A sources in fragment layout (row = lane&15, k-octet = lane>>4)
    const float* gxr0 = x + (rowbase + (lane & 15)) * (long)DK + kh * 512 + ((lane >> 4) << 3);
    const float* gxr1 = gxr0 + 16 * (long)DK;
    const uint4* wfl = WF + ((long)(kh * 16) * 12 + (2 * eh) * 3) * 64 + lane;

    f32x4 acc00 = {0.f,0.f,0.f,0.f}, acc01 = {0.f,0.f,0.f,0.f};
    f32x4 acc10 = {0.f,0.f,0.f,0.f}, acc11 = {0.f,0.f,0.f,0.f};

    // X prefetch: parity sets hold steps c (pa) and c+1 (pb)
    float4 pa00 = *(const float4*)(gxr0);
    float4 pa01 = *(const float4*)(gxr0 + 4);
    float4 pa10 = *(const float4*)(gxr1);
    float4 pa11 = *(const float4*)(gxr1 + 4);
    float4 pb00 = *(const float4*)(gxr0 + 32);
    float4 pb01 = *(const float4*)(gxr0 + 36);
    float4 pb10 = *(const float4*)(gxr1 + 32);
    float4 pb11 = *(const float4*)(gxr1 + 36);

#define STEPBODY(C, P00, P01, P10, P11) do {                                  \
    uint4 bfr[2][3];                                                          \
    _Pragma("unroll")                                                         \
    for (int t = 0; t < 2; ++t)                                               \
        _Pragma("unroll")                                                     \
        for (int p = 0; p < 3; ++p)                                           \
            bfr[t][p] = wfl[((C) * 12 + t * 3 + p) * 64];                     \
    __builtin_amdgcn_sched_barrier(0);                                        \
    float xx0[8] = {P00.x, P00.y, P00.z, P00.w, P01.x, P01.y, P01.z, P01.w};  \
    float xx1[8] = {P10.x, P10.y, P10.z, P10.w, P11.x, P11.y, P11.z, P11.w};  \
    uint4 pl0[3], pl1[3];                                                     \
    split3(xx0, pl0);                                                         \
    split3(xx1, pl1);                                                         \
    __builtin_amdgcn_sched_barrier(0);                                        \
    if ((C) + 2 < NSQ) {                                                      \
        P00 = *(const float4*)(gxr0 + ((C) + 2) * 32);                        \
        P01 = *(const float4*)(gxr0 + ((C) + 2) * 32 + 4);                    \
        P10 = *(const float4*)(gxr1 + ((C) + 2) * 32);                        \
        P11 = *(const float4*)(gxr1 + ((C) + 2) * 32 + 4);                    \
    }                                                                         \
    __builtin_amdgcn_sched_barrier(0);                                        \
    const bf16x8 A00 = __builtin_bit_cast(bf16x8, pl0[0]);                    \
    const bf16x8 A01 = __builtin_bit_cast(bf16x8, pl0[1]);                    \
    const bf16x8 A02 = __builtin_bit_cast(bf16x8, pl0[2]);                    \
    const bf16x8 A10 = __builtin_bit_cast(bf16x8, pl1[0]);                    \
    const bf16x8 A11 = __builtin_bit_cast(bf16x8, pl1[1]);                    \
    const bf16x8 A12 = __builtin_bit_cast(bf16x8, pl1[2]);                    \
    _Pragma("unroll")                                                         \
    for (int t = 0; t < 2; ++t) {                                             \
        const bf16x8 B0 = __builtin_bit_cast(bf16x8, bfr[t][0]);              \
        const bf16x8 B1 = __builtin_bit_cast(bf16x8, bfr[t][1]);              \
        const bf16x8 B2 = __builtin_bit_cast(bf16x8, bfr[t][2]);              \
        f32x4& C0 = t ? acc01 : acc00;                                        \
        f32x4& C1 = t ? acc11 : acc10;                                        \
        C0 = __builtin_amdgcn_mfma_f32_16x16x32_bf16(A00, B0, C0, 0, 0, 0);   \
        C0 = __builtin_amdgcn_mfma_f32_16x16x32_bf16(A00, B1, C0, 0, 0, 0);   \
        C0 = __builtin_amdgcn_mfma_f32_16x16x32_bf16(A01, B0, C0, 0, 0, 0);   \
        C0 = __builtin_amdgcn_mfma_f32_16x16x32_bf16(A01, B1, C0, 0, 0, 0);   \
        C0 = __builtin_amdgcn_mfma_f32_16x16x32_bf16(A00, B2, C0, 0, 0, 0);   \
        C0 = __builtin_amdgcn_mfma_f32_16x16x32_bf16(A02, B0, C0, 0, 0, 0);   \
        C1 = __builtin_amdgcn_mfma_f32_16x16x32_bf16(A10, B0, C1, 0, 0, 0);   \
        C1 = __builtin_amdgcn_mfma_f32_16x16x32_bf16(A10, B1, C1, 0, 0, 0);   \
        C1 = __builtin_amdgcn_mfma_f32_16x16x32_bf16(A11, B0, C1, 0, 0, 0);   \
        C1 = __builtin_amdgcn_mfma_f32_16x16x32_bf16(A11, B1, C1, 0, 0, 0);   \
        C1 = __builtin_amdgcn_mfma_f32_16x16x32_bf16(A10, B2, C1, 0, 0, 0);   \
        C1 = __builtin_amdgcn_mfma_f32_16x16x32_bf16(A12, B0, C1, 0, 0, 0);   \
    }                                                                         \
} while (0)

    for (int c = 0; c < NSQ; c += 2) {
        STEPBODY(c, pa00, pa01, pa10, pa11);
        STEPBODY(c + 1, pb00, pb01, pb10, pb11);
    }
#undef STEPBODY

    // ---- split-K combine: 8 barrier-phases over kh, fixed order (determ.) ----
    __syncthreads();
#pragma unroll
    for (int ph = 0; ph < 8; ++ph) {
        if (kh == ph) {
#pragma unroll
            for (int jj = 0; jj < 4; ++jj) {
                const int r0 = ((lane >> 4) << 2) + jj;
                const int c0 = (2 * eh + 0) * 16 + (lane & 15);
                const int c1 = (2 * eh + 1) * 16 + (lane & 15);
                if (ph == 0) {
                    lg[r0 * 68 + c0] = acc00[jj];
                    lg[r0 * 68 + c1] = acc01[jj];
                    lg[(r0 + 16) * 68 + c0] = acc10[jj];
                    lg[(r0 + 16) * 68 + c1] = acc11[jj];
                } else {
                    lg[r0 * 68 + c0] += acc00[jj];
                    lg[r0 * 68 + c1] += acc01[jj];
                    lg[(r0 + 16) * 68 + c0] += acc10[jj];
                    lg[(r0 + 16) * 68 + c1] += acc11[jj];
                }
            }
        }
        __syncthreads();
    }

    // ---- per-row softmax stats + stable top-2 (one thread per row) ----
    float* rowm   = lg + BM * 68;
    float* rowinv = rowm + BM;
    if (tid < BM) {
        const int row = tid;
        float m = -3.4e38f;
        for (int e = 0; e < NE; ++e) m = fmaxf(m, lg[row * 68 + e]);
        float s = 0.f;
        float v1 = -1.f, v2 = -1.f;
        int   i1 = 0,    i2 = 0;
        for (int e = 0; e < NE; ++e) {
            const float p = __expf(lg[row * 68 + e] - m);
            s += p;
            if (p > v1)      { v2 = v1; i2 = i1; v1 = p; i1 = e; }
            else if (p > v2) { v2 = p; i2 = e; }
        }
        const float inv = 1.f / s;
        rowm[row]   = m;
        rowinv[row] = inv;
        const long grow = rowbase + row;
        const float p1 = v1 * inv, p2 = v2 * inv;
        const float dn = p1 + p2 + 1e-9f;
        out[NIDX + grow * 2 + 0] = (float)i1;
        out[NIDX + grow * 2 + 1] = (float)i2;
        out[NWTS + grow * 2 + 0] = p1 / dn;
        out[NWTS + grow * 2 + 1] = p2 / dn;
    }
    __syncthreads();

    // ---- probs write: first 512 threads x 1 float4, coalesced ----
    if (tid < 512) {
        const int row = tid >> 4;
        const int e0  = (tid & 15) << 2;
        const float m = rowm[row], inv = rowinv[row];
        const long grow = rowbase + row;
        const float4 l4 = *reinterpret_cast<const float4*>(&lg[row * 68 + e0]);
        float4 p;
        p.x = __expf(l4.x - m) * inv;
        p.y = __expf(l4.y - m) * inv;
        p.z = __expf(l4.z - m) * inv;
        p.w = __expf(l4.w - m) * inv;
        *reinterpret_cast<float4*>(&out[grow * (long)NE + e0]) = p;
    }
}

extern "C" void kernel_launch(void* const* d_in, const int* in_sizes, int n_in,
                              void* d_out, int out_size, void* d_ws, size_t ws_size,
                              hipStream_t stream) {
    const float* x = (const float*)d_in[0];
    const float* W = (const float*)d_in[1];
    float* out = (float*)d_out;
    uint4* WF  = (uint4*)d_ws;   // 1.5 MB fragment-ordered W planes

    w_prep<<<dim3(128), dim3(256), 0, stream>>>(W, WF);
    token_router<<<dim3(BT / BM), dim3(1024), 0, stream>>>(x, WF, out);
}

// Round 14
// 124.511 us; speedup vs baseline: 5.2116x; 5.2116x over previous
//
#include <hip/hip_runtime.h>

#define BT 16384
#define DK 4096
#define NE 64
#define BM 32                 // rows per block -> grid 512
#define NSQ 16                // steps per wave (K eighth 512 / 32)
#define NPROBS (BT * NE)
#define NIDX (NPROBS)
#define NWTS (NPROBS + BT * 2)

typedef __bf16 bf16x8 __attribute__((ext_vector_type(8)));
typedef float f32x4 __attribute__((ext_vector_type(4)));

__device__ __forceinline__ unsigned asu(float f) { return __builtin_bit_cast(unsigned, f); }
__device__ __forceinline__ float asf(unsigned u) { return __builtin_bit_cast(float, u); }

// Split 8 f32 into 3 bf16 planes (truncation split; residuals exact in f32).
__device__ __forceinline__ void split3(const float* xx, uint4* pl) {
    unsigned h0[8], h1[8], h2[8];
#pragma unroll
    for (int j = 0; j < 8; ++j) {
        const float xf = xx[j];
        const unsigned a0 = asu(xf) & 0xFFFF0000u;
        const float r1 = xf - asf(a0);
        const unsigned a1 = asu(r1) & 0xFFFF0000u;
        const float r2 = r1 - asf(a1);
        const unsigned a2 = asu(r2) & 0xFFFF0000u;
        h0[j] = a0; h1[j] = a1; h2[j] = a2;
    }
    pl[0] = make_uint4((h0[0] >> 16) | (h0[1] & 0xFFFF0000u), (h0[2] >> 16) | (h0[3] & 0xFFFF0000u),
                       (h0[4] >> 16) | (h0[5] & 0xFFFF0000u), (h0[6] >> 16) | (h0[7] & 0xFFFF0000u));
    pl[1] = make_uint4((h1[0] >> 16) | (h1[1] & 0xFFFF0000u), (h1[2] >> 16) | (h1[3] & 0xFFFF0000u),
                       (h1[4] >> 16) | (h1[5] & 0xFFFF0000u), (h1[6] >> 16) | (h1[7] & 0xFFFF0000u));
    pl[2] = make_uint4((h2[0] >> 16) | (h2[1] & 0xFFFF0000u), (h2[2] >> 16) | (h2[3] & 0xFFFF0000u),
                       (h2[4] >> 16) | (h2[5] & 0xFFFF0000u), (h2[6] >> 16) | (h2[7] & 0xFFFF0000u));
}

// prep: W (64 x 4096 f32) -> 3 bf16 planes in B-fragment order (validated R11/R12).
__global__ __launch_bounds__(256) void w_prep(
    const float* __restrict__ W, uint4* __restrict__ WF)
{
    const int g  = blockIdx.x * 256 + threadIdx.x;
    const int e  = g >> 9;
    const int kg = g & 511;
    const float4 v0 = *(const float4*)(W + (long)e * DK + kg * 8);
    const float4 v1 = *(const float4*)(W + (long)e * DK + kg * 8 + 4);
    float xx[8] = {v0.x, v0.y, v0.z, v0.w, v1.x, v1.y, v1.z, v1.w};
    uint4 pl[3];
    split3(xx, pl);
    const int ks = kg >> 2;
    const int l  = (e & 15) | ((kg & 3) << 4);
    const int et = e >> 4;
#pragma unroll
    for (int p = 0; p < 3; ++p)
        WF[((ks * 4 + et) * 3 + p) * 64 + l] = pl[p];
}

// Main: 512 blocks x 32 rows, 16 waves = (eh expert-half) x (kh K-eighth).
// R14: identical to R13 but UNPINNED register allocation (R13's waves_per_eu(8)
// forced VGPR=32 -> spills, WRITE 1.5 GB). R12's natural allocation for this
// body is 52 VGPR <= 64 -> 8 waves/SIMD at 2 blocks/CU with zero spill.
__global__ __launch_bounds__(1024) void token_router(
    const float* __restrict__ x, const uint4* __restrict__ WF,
    float* __restrict__ out)
{
    __shared__ float lg[BM * 68 + 2 * BM];   // 9 KB: logits + rowm/rowinv

    const int tid  = threadIdx.x;
    const int wv   = tid >> 6;
    const int lane = tid & 63;
    const int eh   = wv & 1;          // expert half
    const int kh   = wv >> 1;         // K eighth 0..7
    const long rowbase = (long)blockIdx.x * BM;

    // A sources in fragment layout (row = lane&15, k-octet = lane>>4)
    const float* gxr0 = x + (rowbase + (lane & 15)) * (long)DK + kh * 512 + ((lane >> 4) << 3);
    const float* gxr1 = gxr0 + 16 * (long)DK;
    const uint4* wfl = WF + ((long)(kh * 16) * 12 + (2 * eh) * 3) * 64 + lane;

    f32x4 acc00 = {0.f,0.f,0.f,0.f}, acc01 = {0.f,0.f,0.f,0.f};
    f32x4 acc10 = {0.f,0.f,0.f,0.f}, acc11 = {0.f,0.f,0.f,0.f};

    // X prefetch: parity sets hold steps c (pa) and c+1 (pb)
    float4 pa00 = *(const float4*)(gxr0);
    float4 pa01 = *(const float4*)(gxr0 + 4);
    float4 pa10 = *(const float4*)(gxr1);
    float4 pa11 = *(const float4*)(gxr1 + 4);
    float4 pb00 = *(const float4*)(gxr0 + 32);
    float4 pb01 = *(const float4*)(gxr0 + 36);
    float4 pb10 = *(const float4*)(gxr1 + 32);
    float4 pb11 = *(const float4*)(gxr1 + 36);

#define STEPBODY(C, P00, P01, P10, P11) do {                                  \
    uint4 bfr[2][3];                                                          \
    _Pragma("unroll")                                                         \
    for (int t = 0; t < 2; ++t)                                               \
        _Pragma("unroll")                                                     \
        for (int p = 0; p < 3; ++p)                                           \
            bfr[t][p] = wfl[((C) * 12 + t * 3 + p) * 64];                     \
    __builtin_amdgcn_sched_barrier(0);                                        \
    float xx0[8] = {P00.x, P00.y, P00.z, P00.w, P01.x, P01.y, P01.z, P01.w};  \
    float xx1[8] = {P10.x, P10.y, P10.z, P10.w, P11.x, P11.y, P11.z, P11.w};  \
    uint4 pl0[3], pl1[3];                                                     \
    split3(xx0, pl0);                                                         \
    split3(xx1, pl1);                                                         \
    __builtin_amdgcn_sched_barrier(0);                                        \
    if ((C) + 2 < NSQ) {                                                      \
        P00 = *(const float4*)(gxr0 + ((C) + 2) * 32);                        \
        P01 = *(const float4*)(gxr0 + ((C) + 2) * 32 + 4);                    \
        P10 = *(const float4*)(gxr1 + ((C) + 2) * 32);                        \
        P11 = *(const float4*)(gxr1 + ((C) + 2) * 32 + 4);                    \
    }                                                                         \
    __builtin_amdgcn_sched_barrier(0);                                        \
    const bf16x8 A00 = __builtin_bit_cast(bf16x8, pl0[0]);                    \
    const bf16x8 A01 = __builtin_bit_cast(bf16x8, pl0[1]);                    \
    const bf16x8 A02 = __builtin_bit_cast(bf16x8, pl0[2]);                    \
    const bf16x8 A10 = __builtin_bit_cast(bf16x8, pl1[0]);                    \
    const bf16x8 A11 = __builtin_bit_cast(bf16x8, pl1[1]);                    \
    const bf16x8 A12 = __builtin_bit_cast(bf16x8, pl1[2]);                    \
    _Pragma("unroll")                                                         \
    for (int t = 0; t < 2; ++t) {                                             \
        const bf16x8 B0 = __builtin_bit_cast(bf16x8, bfr[t][0]);              \
        const bf16x8 B1 = __builtin_bit_cast(bf16x8, bfr[t][1]);              \
        const bf16x8 B2 = __builtin_bit_cast(bf16x8, bfr[t][2]);              \
        f32x4& C0 = t ? acc01 : acc00;                                        \
        f32x4& C1 = t ? acc11 : acc10;                                        \
        C0 = __builtin_amdgcn_mfma_f32_16x16x32_bf16(A00, B0, C0, 0, 0, 0);   \
        C0 = __builtin_amdgcn_mfma_f32_16x16x32_bf16(A00, B1, C0, 0, 0, 0);   \
        C0 = __builtin_amdgcn_mfma_f32_16x16x32_bf16(A01, B0, C0, 0, 0, 0);   \
        C0 = __builtin_amdgcn_mfma_f32_16x16x32_bf16(A01, B1, C0, 0, 0, 0);   \
        C0 = __builtin_amdgcn_mfma_f32_16x16x32_bf16(A00, B2, C0, 0, 0, 0);   \
        C0 = __builtin_amdgcn_mfma_f32_16x16x32_bf16(A02, B0, C0, 0, 0, 0);   \
        C1 = __builtin_amdgcn_mfma_f32_16x16x32_bf16(A10, B0, C1, 0, 0, 0);   \
        C1 = __builtin_amdgcn_mfma_f32_16x16x32_bf16(A10, B1, C1, 0, 0, 0);   \
        C1 = __builtin_amdgcn_mfma_f32_16x16x32_bf16(A11, B0, C1, 0, 0, 0);   \
        C1 = __builtin_amdgcn_mfma_f32_16x16x32_bf16(A11, B1, C1, 0, 0, 0);   \
        C1 = __builtin_amdgcn_mfma_f32_16x16x32_bf16(A10, B2, C1, 0, 0, 0);   \
        C1 = __builtin_amdgcn_mfma_f32_16x16x32_bf16(A12, B0, C1, 0, 0, 0);   \
    }                                                                         \
} while (0)

    for (int c = 0; c < NSQ; c += 2) {
        STEPBODY(c, pa00, pa01, pa10, pa11);
        STEPBODY(c + 1, pb00, pb01, pb10, pb11);
    }
#undef STEPBODY

    // ---- split-K combine: 8 barrier-phases over kh, fixed order (determ.) ----
    __syncthreads();
#pragma unroll
    for (int ph = 0; ph < 8; ++ph) {
        if (kh == ph) {
#pragma unroll
            for (int jj = 0; jj < 4; ++jj) {
                const int r0 = ((lane >> 4) << 2) + jj;
                const int c0 = (2 * eh + 0) * 16 + (lane & 15);
                const int c1 = (2 * eh + 1) * 16 + (lane & 15);
                if (ph == 0) {
                    lg[r0 * 68 + c0] = acc00[jj];
                    lg[r0 * 68 + c1] = acc01[jj];
                    lg[(r0 + 16) * 68 + c0] = acc10[jj];
                    lg[(r0 + 16) * 68 + c1] = acc11[jj];
                } else {
                    lg[r0 * 68 + c0] += acc00[jj];
                    lg[r0 * 68 + c1] += acc01[jj];
                    lg[(r0 + 16) * 68 + c0] += acc10[jj];
                    lg[(r0 + 16) * 68 + c1] += acc11[jj];
                }
            }
        }
        __syncthreads();
    }

    // ---- per-row softmax stats + stable top-2 (one thread per row) ----
    float* rowm   = lg + BM * 68;
    float* rowinv = rowm + BM;
    if (tid < BM) {
        const int row = tid;
        float m = -3.4e38f;
        for (int e = 0; e < NE; ++e) m = fmaxf(m, lg[row * 68 + e]);
        float s = 0.f;
        float v1 = -1.f, v2 = -1.f;
        int   i1 = 0,    i2 = 0;
        for (int e = 0; e < NE; ++e) {
            const float p = __expf(lg[row * 68 + e] - m);
            s += p;
            if (p > v1)      { v2 = v1; i2 = i1; v1 = p; i1 = e; }
            else if (p > v2) { v2 = p; i2 = e; }
        }
        const float inv = 1.f / s;
        rowm[row]   = m;
        rowinv[row] = inv;
        const long grow = rowbase + row;
        const float p1 = v1 * inv, p2 = v2 * inv;
        const float dn = p1 + p2 + 1e-9f;
        out[NIDX + grow * 2 + 0] = (float)i1;
        out[NIDX + grow * 2 + 1] = (float)i2;
        out[NWTS + grow * 2 + 0] = p1 / dn;
        out[NWTS + grow * 2 + 1] = p2 / dn;
    }
    __syncthreads();

    // ---- probs write: first 512 threads x 1 float4, coalesced ----
    if (tid < 512) {
        const int row = tid >> 4;
        const int e0  = (tid & 15) << 2;
        const float m = rowm[row], inv = rowinv[row];
        const long grow = rowbase + row;
        const float4 l4 = *reinterpret_cast<const float4*>(&lg[row * 68 + e0]);
        float4 p;
        p.x = __expf(l4.x - m) * inv;
        p.y = __expf(l4.y - m) * inv;
        p.z = __expf(l4.z - m) * inv;
        p.w = __expf(l4.w - m) * inv;
        *reinterpret_cast<float4*>(&out[grow * (long)NE + e0]) = p;
    }
}

extern "C" void kernel_launch(void* const* d_in, const int* in_sizes, int n_in,
                              void* d_out, int out_size, void* d_ws, size_t ws_size,
                              hipStream_t stream) {
    const float* x = (const float*)d_in[0];
    const float* W = (const float*)d_in[1];
    float* out = (float*)d_out;
    uint4* WF  = (uint4*)d_ws;   // 1.5 MB fragment-ordered W planes

    w_prep<<<dim3(128), dim3(256), 0, stream>>>(W, WF);
    token_router<<<dim3(BT / BM), dim3(1024), 0, stream>>>(x, WF, out);
}

// Round 15
// 114.127 us; speedup vs baseline: 5.6857x; 1.0910x over previous
//
#include <hip/hip_runtime.h>

#define BT 16384
#define DK 4096
#define NE 64
#define BM 32                 // rows per block -> grid 512, 2 blocks/CU
#define NSQ 32                // steps per wave (K quarter 1024 / 32)
#define NPROBS (BT * NE)
#define NIDX (NPROBS)
#define NWTS (NPROBS + BT * 2)

typedef __bf16 bf16x8 __attribute__((ext_vector_type(8)));
typedef float f32x4 __attribute__((ext_vector_type(4)));

__device__ __forceinline__ unsigned asu(float f) { return __builtin_bit_cast(unsigned, f); }
__device__ __forceinline__ float asf(unsigned u) { return __builtin_bit_cast(float, u); }

// Split 8 f32 into 3 bf16 planes (truncation split; residuals exact in f32).
__device__ __forceinline__ void split3(const float* xx, uint4* pl) {
    unsigned h0[8], h1[8], h2[8];
#pragma unroll
    for (int j = 0; j < 8; ++j) {
        const float xf = xx[j];
        const unsigned a0 = asu(xf) & 0xFFFF0000u;
        const float r1 = xf - asf(a0);
        const unsigned a1 = asu(r1) & 0xFFFF0000u;
        const float r2 = r1 - asf(a1);
        const unsigned a2 = asu(r2) & 0xFFFF0000u;
        h0[j] = a0; h1[j] = a1; h2[j] = a2;
    }
    pl[0] = make_uint4((h0[0] >> 16) | (h0[1] & 0xFFFF0000u), (h0[2] >> 16) | (h0[3] & 0xFFFF0000u),
                       (h0[4] >> 16) | (h0[5] & 0xFFFF0000u), (h0[6] >> 16) | (h0[7] & 0xFFFF0000u));
    pl[1] = make_uint4((h1[0] >> 16) | (h1[1] & 0xFFFF0000u), (h1[2] >> 16) | (h1[3] & 0xFFFF0000u),
                       (h1[4] >> 16) | (h1[5] & 0xFFFF0000u), (h1[6] >> 16) | (h1[7] & 0xFFFF0000u));
    pl[2] = make_uint4((h2[0] >> 16) | (h2[1] & 0xFFFF0000u), (h2[2] >> 16) | (h2[3] & 0xFFFF0000u),
                       (h2[4] >> 16) | (h2[5] & 0xFFFF0000u), (h2[6] >> 16) | (h2[7] & 0xFFFF0000u));
}

// prep: W (64 x 4096 f32) -> 3 bf16 planes in B-fragment order (validated R11+).
__global__ __launch_bounds__(256) void w_prep(
    const float* __restrict__ W, uint4* __restrict__ WF)
{
    const int g  = blockIdx.x * 256 + threadIdx.x;
    const int e  = g >> 9;
    const int kg = g & 511;
    const float4 v0 = *(const float4*)(W + (long)e * DK + kg * 8);
    const float4 v1 = *(const float4*)(W + (long)e * DK + kg * 8 + 4);
    float xx[8] = {v0.x, v0.y, v0.z, v0.w, v1.x, v1.y, v1.z, v1.w};
    uint4 pl[3];
    split3(xx, pl);
    const int ks = kg >> 2;
    const int l  = (e & 15) | ((kg & 3) << 4);
    const int et = e >> 4;
#pragma unroll
    for (int p = 0; p < 3; ++p)
        WF[((ks * 4 + et) * 3 + p) * 64 + l] = pl[p];
}

// Main: 512 blocks x 32 rows, 8 waves = (eh expert-half) x (kh K-quarter).
// R15: REGISTER-DOUBLE-BUFFERED B. Per step: issue B(c+1) into the spare set;
// split3(X(c)) -- whose vmcnt wait drains X(c) AND the older B(c), so the
// MFMAs need no wait; issue X(c+1); 24 MFMA with B(c). Every VMEM value is
// consumed a full step after issue -> in-order vmcnt retirement costs zero.
__global__ __launch_bounds__(512) void token_router(
    const float* __restrict__ x, const uint4* __restrict__ WF,
    float* __restrict__ out)
{
    __shared__ float lg[BM * 68 + 2 * BM];   // 9 KB: logits + rowm/rowinv

    const int tid  = threadIdx.x;
    const int wv   = tid >> 6;
    const int lane = tid & 63;
    const int eh   = wv & 1;          // expert half
    const int kh   = wv >> 1;         // K quarter 0..3
    const long rowbase = (long)blockIdx.x * BM;

    // A sources in fragment layout (row = lane&15, k-octet = lane>>4)
    const float* gxr0 = x + (rowbase + (lane & 15)) * (long)DK + kh * 1024 + ((lane >> 4) << 3);
    const float* gxr1 = gxr0 + 16 * (long)DK;
    const uint4* wfl = WF + ((long)(kh * 32) * 12 + (2 * eh) * 3) * 64 + lane;

    f32x4 acc00 = {0.f,0.f,0.f,0.f}, acc01 = {0.f,0.f,0.f,0.f};
    f32x4 acc10 = {0.f,0.f,0.f,0.f}, acc11 = {0.f,0.f,0.f,0.f};

    // B register double-buffer: set a / set b (named, static indices only)
    uint4 ba[2][3], bb[2][3];
    // X hold (distance 1)
    float4 p00, p01, p10, p11;

    // prologue: B(0) -> set a ; X(0) -> hold
#pragma unroll
    for (int t = 0; t < 2; ++t)
#pragma unroll
        for (int p = 0; p < 3; ++p)
            ba[t][p] = wfl[(t * 3 + p) * 64];
    p00 = *(const float4*)(gxr0);
    p01 = *(const float4*)(gxr0 + 4);
    p10 = *(const float4*)(gxr1);
    p11 = *(const float4*)(gxr1 + 4);

#define STEPBODY(C, BCUR, BNXT) do {                                          \
    if ((C) + 1 < NSQ) {                                                      \
        _Pragma("unroll")                                                     \
        for (int t = 0; t < 2; ++t)                                           \
            _Pragma("unroll")                                                 \
            for (int p = 0; p < 3; ++p)                                       \
                BNXT[t][p] = wfl[(((C) + 1) * 12 + t * 3 + p) * 64];          \
    }                                                                         \
    float xx0[8] = {p00.x, p00.y, p00.z, p00.w, p01.x, p01.y, p01.z, p01.w};  \
    float xx1[8] = {p10.x, p10.y, p10.z, p10.w, p11.x, p11.y, p11.z, p11.w};  \
    uint4 pl0[3], pl1[3];                                                     \
    split3(xx0, pl0);                                                         \
    split3(xx1, pl1);                                                         \
    if ((C) + 1 < NSQ) {                                                      \
        p00 = *(const float4*)(gxr0 + ((C) + 1) * 32);                        \
        p01 = *(const float4*)(gxr0 + ((C) + 1) * 32 + 4);                    \
        p10 = *(const float4*)(gxr1 + ((C) + 1) * 32);                        \
        p11 = *(const float4*)(gxr1 + ((C) + 1) * 32 + 4);                    \
    }                                                                         \
    const bf16x8 A00 = __builtin_bit_cast(bf16x8, pl0[0]);                    \
    const bf16x8 A01 = __builtin_bit_cast(bf16x8, pl0[1]);                    \
    const bf16x8 A02 = __builtin_bit_cast(bf16x8, pl0[2]);                    \
    const bf16x8 A10 = __builtin_bit_cast(bf16x8, pl1[0]);                    \
    const bf16x8 A11 = __builtin_bit_cast(bf16x8, pl1[1]);                    \
    const bf16x8 A12 = __builtin_bit_cast(bf16x8, pl1[2]);                    \
    _Pragma("unroll")                                                         \
    for (int t = 0; t < 2; ++t) {                                             \
        const bf16x8 B0 = __builtin_bit_cast(bf16x8, BCUR[t][0]);             \
        const bf16x8 B1 = __builtin_bit_cast(bf16x8, BCUR[t][1]);             \
        const bf16x8 B2 = __builtin_bit_cast(bf16x8, BCUR[t][2]);             \
        f32x4& C0 = t ? acc01 : acc00;                                        \
        f32x4& C1 = t ? acc11 : acc10;                                        \
        C0 = __builtin_amdgcn_mfma_f32_16x16x32_bf16(A00, B0, C0, 0, 0, 0);   \
        C0 = __builtin_amdgcn_mfma_f32_16x16x32_bf16(A00, B1, C0, 0, 0, 0);   \
        C0 = __builtin_amdgcn_mfma_f32_16x16x32_bf16(A01, B0, C0, 0, 0, 0);   \
        C0 = __builtin_amdgcn_mfma_f32_16x16x32_bf16(A01, B1, C0, 0, 0, 0);   \
        C0 = __builtin_amdgcn_mfma_f32_16x16x32_bf16(A00, B2, C0, 0, 0, 0);   \
        C0 = __builtin_amdgcn_mfma_f32_16x16x32_bf16(A02, B0, C0, 0, 0, 0);   \
        C1 = __builtin_amdgcn_mfma_f32_16x16x32_bf16(A10, B0, C1, 0, 0, 0);   \
        C1 = __builtin_amdgcn_mfma_f32_16x16x32_bf16(A10, B1, C1, 0, 0, 0);   \
        C1 = __builtin_amdgcn_mfma_f32_16x16x32_bf16(A11, B0, C1, 0, 0, 0);   \
        C1 = __builtin_amdgcn_mfma_f32_16x16x32_bf16(A11, B1, C1, 0, 0, 0);   \
        C1 = __builtin_amdgcn_mfma_f32_16x16x32_bf16(A10, B2, C1, 0, 0, 0);   \
        C1 = __builtin_amdgcn_mfma_f32_16x16x32_bf16(A12, B0, C1, 0, 0, 0);   \
    }                                                                         \
} while (0)

    for (int c = 0; c < NSQ; c += 2) {
        STEPBODY(c, ba, bb);
        STEPBODY(c + 1, bb, ba);
    }
#undef STEPBODY

    // ---- split-K combine: 4 barrier-phases over kh, fixed order (determ.) ----
    __syncthreads();
#pragma unroll
    for (int ph = 0; ph < 4; ++ph) {
        if (kh == ph) {
#pragma unroll
            for (int jj = 0; jj < 4; ++jj) {
                const int r0 = ((lane >> 4) << 2) + jj;
                const int c0 = (2 * eh + 0) * 16 + (lane & 15);
                const int c1 = (2 * eh + 1) * 16 + (lane & 15);
                if (ph == 0) {
                    lg[r0 * 68 + c0] = acc00[jj];
                    lg[r0 * 68 + c1] = acc01[jj];
                    lg[(r0 + 16) * 68 + c0] = acc10[jj];
                    lg[(r0 + 16) * 68 + c1] = acc11[jj];
                } else {
                    lg[r0 * 68 + c0] += acc00[jj];
                    lg[r0 * 68 + c1] += acc01[jj];
                    lg[(r0 + 16) * 68 + c0] += acc10[jj];
                    lg[(r0 + 16) * 68 + c1] += acc11[jj];
                }
            }
        }
        __syncthreads();
    }

    // ---- per-row softmax stats + stable top-2 (one thread per row) ----
    float* rowm   = lg + BM * 68;
    float* rowinv = rowm + BM;
    if (tid < BM) {
        const int row = tid;
        float m = -3.4e38f;
        for (int e = 0; e < NE; ++e) m = fmaxf(m, lg[row * 68 + e]);
        float s = 0.f;
        float v1 = -1.f, v2 = -1.f;
        int   i1 = 0,    i2 = 0;
        for (int e = 0; e < NE; ++e) {
            const float p = __expf(lg[row * 68 + e] - m);
            s += p;
            if (p > v1)      { v2 = v1; i2 = i1; v1 = p; i1 = e; }
            else if (p > v2) { v2 = p; i2 = e; }
        }
        const float inv = 1.f / s;
        rowm[row]   = m;
        rowinv[row] = inv;
        const long grow = rowbase + row;
        const float p1 = v1 * inv, p2 = v2 * inv;
        const float dn = p1 + p2 + 1e-9f;
        out[NIDX + grow * 2 + 0] = (float)i1;
        out[NIDX + grow * 2 + 1] = (float)i2;
        out[NWTS + grow * 2 + 0] = p1 / dn;
        out[NWTS + grow * 2 + 1] = p2 / dn;
    }
    __syncthreads();

    // ---- probs write: 512 threads x 1 float4, coalesced ----
    {
        const int row = tid >> 4;
        const int e0  = (tid & 15) << 2;
        const float m = rowm[row], inv = rowinv[row];
        const long grow = rowbase + row;
        const float4 l4 = *reinterpret_cast<const float4*>(&lg[row * 68 + e0]);
        float4 p;
        p.x = __expf(l4.x - m) * inv;
        p.y = __expf(l4.y - m) * inv;
        p.z = __expf(l4.z - m) * inv;
        p.w = __expf(l4.w - m) * inv;
        *reinterpret_cast<float4*>(&out[grow * (long)NE + e0]) = p;
    }
}

extern "C" void kernel_launch(void* const* d_in, const int* in_sizes, int n_in,
                              void* d_out, int out_size, void* d_ws, size_t ws_size,
                              hipStream_t stream) {
    const float* x = (const float*)d_in[0];
    const float* W = (const float*)d_in[1];
    float* out = (float*)d_out;
    uint4* WF  = (uint4*)d_ws;   // 1.5 MB fragment-ordered W planes

    w_prep<<<dim3(128), dim3(256), 0, stream>>>(W, WF);
    token_router<<<dim3(BT / BM), dim3(512), 0, stream>>>(x, WF, out);
}